// Round 2
// baseline (351.094 us; speedup 1.0000x reference)
//
#include <hip/hip_runtime.h>
#include <cmath>

#define NLEVELS 16
#define HMASK   0x7FFFFu
#define NPTS    524288
#define NBUCKET 32768          // 32^3 Morton buckets

typedef float v4f __attribute__((ext_vector_type(4)));
typedef float v2f __attribute__((ext_vector_type(2)));

struct LevelParams {
    float cell[NLEVELS];       // fp32 value of 1.0f / (float)RES[l], matching numpy
};

// ---------------------------------------------------------------------------
// Morton bucketing (5 bits/axis)
// ---------------------------------------------------------------------------
__device__ __forceinline__ unsigned spread5(unsigned v) {
    return (v & 1u) | ((v & 2u) << 2) | ((v & 4u) << 4) |
           ((v & 8u) << 6) | ((v & 16u) << 8);
}

__device__ __forceinline__ unsigned morton_key(float x, float y, float z) {
    unsigned bx = min(31u, (unsigned)(x * 32.0f));
    unsigned by = min(31u, (unsigned)(y * 32.0f));
    unsigned bz = min(31u, (unsigned)(z * 32.0f));
    return spread5(bx) | (spread5(by) << 1) | (spread5(bz) << 2);
}

// ---------------------------------------------------------------------------
// EXACT replication of the numpy fp32 chain: hashes + trilinear weights.
// ---------------------------------------------------------------------------
__device__ __forceinline__ void ngp_hash(
    float x, float y, float z, float cell, unsigned* __restrict__ h,
    float& dx, float& dy, float& dz)
{
    const float ux = x / cell;
    const float uy = y / cell;
    const float uz = z / cell;
    const float fx = floorf(ux);
    const float fy = floorf(uy);
    const float fz = floorf(uz);
    dx = ux - fx;
    dy = uy - fy;
    dz = uz - fz;

    const unsigned ix = (unsigned)(int)fx;
    const unsigned iy = (unsigned)(int)fy;
    const unsigned iz = (unsigned)(int)fz;

    const unsigned hx0 = ix;
    const unsigned hx1 = ix + 1u;
    const unsigned hy0 = iy * 2654435761u;
    const unsigned hy1 = (iy + 1u) * 2654435761u;
    const unsigned hz0 = iz * 805459861u;
    const unsigned hz1 = (iz + 1u) * 805459861u;

    h[0] = (hx0 ^ hy0 ^ hz0) & HMASK;
    h[1] = (hx0 ^ hy0 ^ hz1) & HMASK;
    h[2] = (hx0 ^ hy1 ^ hz0) & HMASK;
    h[3] = (hx0 ^ hy1 ^ hz1) & HMASK;
    h[4] = (hx1 ^ hy0 ^ hz0) & HMASK;
    h[5] = (hx1 ^ hy0 ^ hz1) & HMASK;
    h[6] = (hx1 ^ hy1 ^ hz0) & HMASK;
    h[7] = (hx1 ^ hy1 ^ hz1) & HMASK;
}

__device__ __forceinline__ void ngp_weights(
    float dx, float dy, float dz, float* __restrict__ w)
{
    const float wx0 = 1.0f - dx;
    const float wy0 = 1.0f - dy;
    const float wz0 = 1.0f - dz;
    const float p00 = wx0 * wy0;
    const float p01 = wx0 * dy;
    const float p10 = dx * wy0;
    const float p11 = dx * dy;
    w[0] = p00 * wz0;
    w[1] = p00 * dz;
    w[2] = p01 * wz0;
    w[3] = p01 * dz;
    w[4] = p10 * wz0;
    w[5] = p10 * dz;
    w[6] = p11 * wz0;
    w[7] = p11 * dz;
}

__device__ __forceinline__ v2f ngp_combine(
    const float* __restrict__ w, const v2f* __restrict__ e)
{
    // Same accumulation order as the verified baseline (absmax 4.8e-7).
    float c0 = w[0] * e[0].x;
    float c1 = w[0] * e[0].y;
    #pragma unroll
    for (int c = 1; c < 8; ++c) {
        c0 += w[c] * e[c].x;
        c1 += w[c] * e[c].y;
    }
    v2f r = { c0, c1 };
    return r;
}

// ---------------------------------------------------------------------------
// Sort kernel A: histogram of Morton buckets.
// ---------------------------------------------------------------------------
__global__ __launch_bounds__(256) void bucket_count(
    const float* __restrict__ xyz, unsigned* __restrict__ counts)
{
    const int n = blockIdx.x * 256 + threadIdx.x;
    const float x = xyz[3 * n + 0];
    const float y = xyz[3 * n + 1];
    const float z = xyz[3 * n + 2];
    atomicAdd(&counts[morton_key(x, y, z)], 1u);
}

// ---------------------------------------------------------------------------
// Sort kernel B: exclusive prefix sum of 32768 counts -> cursor[].
// One block / 1024 threads. Global traffic COALESCED; LDS XOR swizzle
// (idx ^ ((idx>>5)&31)) is conflict-free in both access phases.
// NEW: wave-level shfl_up scan -> 3 barriers total (was ~22).
// ---------------------------------------------------------------------------
__global__ __launch_bounds__(1024) void bucket_scan(
    const unsigned* __restrict__ counts, unsigned* __restrict__ cursor)
{
    __shared__ unsigned c[NBUCKET];      // 128 KiB (gfx950 LDS = 160 KiB)
    __shared__ unsigned wsum[16];
    const unsigned t = threadIdx.x;
    const unsigned lane = t & 63u;
    const unsigned wid = t >> 6;

    #pragma unroll
    for (int i = 0; i < 32; ++i) {
        const unsigned idx = (unsigned)i * 1024u + t;
        c[idx ^ ((idx >> 5) & 31u)] = counts[idx];
    }
    __syncthreads();

    unsigned s = 0;
    #pragma unroll
    for (int i = 0; i < 32; ++i) {
        const unsigned idx = t * 32u + (unsigned)i;
        s += c[idx ^ ((idx >> 5) & 31u)];
    }

    // wave-inclusive scan of per-thread sums (no barriers)
    unsigned v = s;
    #pragma unroll
    for (unsigned off = 1; off < 64; off <<= 1) {
        const unsigned u = __shfl_up(v, off);
        if (lane >= off) v += u;
    }
    if (lane == 63u) wsum[wid] = v;
    __syncthreads();

    unsigned woff = 0;
    #pragma unroll
    for (unsigned w = 0; w < 16; ++w)
        woff += (w < wid) ? wsum[w] : 0u;

    unsigned excl = woff + (v - s);   // exclusive prefix of this thread's segment
    #pragma unroll
    for (int i = 0; i < 32; ++i) {
        const unsigned idx = t * 32u + (unsigned)i;
        const unsigned sw  = idx ^ ((idx >> 5) & 31u);
        const unsigned tmp = c[sw];
        c[sw] = excl;
        excl += tmp;
    }
    __syncthreads();

    #pragma unroll
    for (int i = 0; i < 32; ++i) {
        const unsigned idx = (unsigned)i * 1024u + t;
        cursor[idx] = c[idx ^ ((idx >> 5) & 31u)];
    }
}

// ---------------------------------------------------------------------------
// Sort kernel C: scatter points into sorted order, PACKED as (x,y,z,bits(n)).
// ---------------------------------------------------------------------------
__global__ __launch_bounds__(256) void bucket_scatter(
    const float* __restrict__ xyz, unsigned* __restrict__ cursor,
    v4f* __restrict__ pts)
{
    const int n = blockIdx.x * 256 + threadIdx.x;
    const float x = xyz[3 * n + 0];
    const float y = xyz[3 * n + 1];
    const float z = xyz[3 * n + 2];
    const unsigned key = morton_key(x, y, z);
    const unsigned p = atomicAdd(&cursor[key], 1u);
    v4f v = { x, y, z, __uint_as_float((unsigned)n) };
    pts[p] = v;
}

// ---------------------------------------------------------------------------
// Phase 1: one block = 512 sorted points x ONE level (2 points per thread),
// level-major dispatch (1024 % 8 == 0 keeps chunk -> XCD mapping stable
// across levels, so each XCD holds its own copy of the current table in L2).
//
// MLP experiment: the 8-gather-then-drain pattern exposes too little
// memory-level parallelism per wave (rate ~ outstanding/latency). Issue all
// 16 gathers for two points, then vmcnt(8) / combine A / vmcnt(0) /
// combine B. The waitcnts are tied to the loaded values via "+v" in/outs so
// consumers cannot be hoisted above them (learn_hip rule #18 analog).
//
// Fine levels (>= 5: table footprint >> L1) bypass L1 with sc0; ws stores
// are non-temporal so 64 MB of streaming output doesn't evict the table.
// ---------------------------------------------------------------------------
__global__ __launch_bounds__(256) void ngp_phase1(
    const v4f* __restrict__ pts,
    const float* __restrict__ tables,
    v2f* __restrict__ ws,             // [L][N] v2f, sorted point order
    LevelParams lp)
{
    const unsigned b = blockIdx.x;
    const int level = (int)(b >> 10);
    const int chunk = (int)(b & 1023u);
    const int p0 = chunk * 512 + threadIdx.x;
    const int p1 = p0 + 256;

    const v4f qa = pts[p0];
    const v4f qb = pts[p1];

    const float cell = lp.cell[level];
    const v2f* __restrict__ tab = (const v2f*)tables + ((size_t)level << 19);

    unsigned ha[8], hb[8];
    float dxa, dya, dza, dxb, dyb, dzb;
    ngp_hash(qa.x, qa.y, qa.z, cell, ha, dxa, dya, dza);
    ngp_hash(qb.x, qb.y, qb.z, cell, hb, dxb, dyb, dzb);

    v2f ea[8], eb[8];
    if (level >= 5) {
        v2f a0, a1, a2, a3, a4, a5, a6, a7;
        v2f b0, b1, b2, b3, b4, b5, b6, b7;
        // Issue all 16 L1-bypass gathers back-to-back (no waitcnt yet).
        asm volatile(
            "global_load_dwordx2 %0, %8, off sc0\n\t"
            "global_load_dwordx2 %1, %9, off sc0\n\t"
            "global_load_dwordx2 %2, %10, off sc0\n\t"
            "global_load_dwordx2 %3, %11, off sc0\n\t"
            "global_load_dwordx2 %4, %12, off sc0\n\t"
            "global_load_dwordx2 %5, %13, off sc0\n\t"
            "global_load_dwordx2 %6, %14, off sc0\n\t"
            "global_load_dwordx2 %7, %15, off sc0"
            : "=&v"(a0), "=&v"(a1), "=&v"(a2), "=&v"(a3),
              "=&v"(a4), "=&v"(a5), "=&v"(a6), "=&v"(a7)
            : "v"(tab + ha[0]), "v"(tab + ha[1]), "v"(tab + ha[2]), "v"(tab + ha[3]),
              "v"(tab + ha[4]), "v"(tab + ha[5]), "v"(tab + ha[6]), "v"(tab + ha[7]));
        asm volatile(
            "global_load_dwordx2 %0, %8, off sc0\n\t"
            "global_load_dwordx2 %1, %9, off sc0\n\t"
            "global_load_dwordx2 %2, %10, off sc0\n\t"
            "global_load_dwordx2 %3, %11, off sc0\n\t"
            "global_load_dwordx2 %4, %12, off sc0\n\t"
            "global_load_dwordx2 %5, %13, off sc0\n\t"
            "global_load_dwordx2 %6, %14, off sc0\n\t"
            "global_load_dwordx2 %7, %15, off sc0"
            : "=&v"(b0), "=&v"(b1), "=&v"(b2), "=&v"(b3),
              "=&v"(b4), "=&v"(b5), "=&v"(b6), "=&v"(b7)
            : "v"(tab + hb[0]), "v"(tab + hb[1]), "v"(tab + hb[2]), "v"(tab + hb[3]),
              "v"(tab + hb[4]), "v"(tab + hb[5]), "v"(tab + hb[6]), "v"(tab + hb[7]));
        // Wait for point A's 8 loads only (B's 8 stay in flight); the "+v"
        // in/outs make every consumer of a* data-depend on this waitcnt.
        asm volatile(
            "s_waitcnt vmcnt(8)"
            : "+v"(a0), "+v"(a1), "+v"(a2), "+v"(a3),
              "+v"(a4), "+v"(a5), "+v"(a6), "+v"(a7));
        ea[0] = a0; ea[1] = a1; ea[2] = a2; ea[3] = a3;
        ea[4] = a4; ea[5] = a5; ea[6] = a6; ea[7] = a7;

        float wa[8];
        ngp_weights(dxa, dya, dza, wa);
        const v2f ra = ngp_combine(wa, ea);

        asm volatile(
            "s_waitcnt vmcnt(0)"
            : "+v"(b0), "+v"(b1), "+v"(b2), "+v"(b3),
              "+v"(b4), "+v"(b5), "+v"(b6), "+v"(b7));
        eb[0] = b0; eb[1] = b1; eb[2] = b2; eb[3] = b3;
        eb[4] = b4; eb[5] = b5; eb[6] = b6; eb[7] = b7;

        float wb[8];
        ngp_weights(dxb, dyb, dzb, wb);
        const v2f rb = ngp_combine(wb, eb);

        __builtin_nontemporal_store(ra, &ws[(size_t)level * NPTS + p0]);
        __builtin_nontemporal_store(rb, &ws[(size_t)level * NPTS + p1]);
    } else {
        #pragma unroll
        for (int c = 0; c < 8; ++c) ea[c] = tab[ha[c]];
        #pragma unroll
        for (int c = 0; c < 8; ++c) eb[c] = tab[hb[c]];

        float wa[8], wb[8];
        ngp_weights(dxa, dya, dza, wa);
        ngp_weights(dxb, dyb, dzb, wb);
        const v2f ra = ngp_combine(wa, ea);
        const v2f rb = ngp_combine(wb, eb);

        __builtin_nontemporal_store(ra, &ws[(size_t)level * NPTS + p0]);
        __builtin_nontemporal_store(rb, &ws[(size_t)level * NPTS + p1]);
    }
}

// ---------------------------------------------------------------------------
// Phase 2: un-permute + transpose ws[l][p] -> out[perm[p]][32] via LDS.
// perm comes from the packed pts[].w. Streaming data uses non-temporal
// accesses. LDS stride 257 v2f: worst 2-way conflict (free).
// ---------------------------------------------------------------------------
#define P2S 257

__global__ __launch_bounds__(256) void ngp_phase2(
    const v2f* __restrict__ ws,
    const v4f* __restrict__ pts,
    float* __restrict__ out)
{
    __shared__ v2f lds[NLEVELS * P2S];
    __shared__ unsigned nperm[256];
    const unsigned base = blockIdx.x * 256;
    const unsigned t = threadIdx.x;

    nperm[t] = __float_as_uint(pts[base + t].w);
    #pragma unroll
    for (int l = 0; l < NLEVELS; ++l)
        lds[l * P2S + t] =
            __builtin_nontemporal_load(&ws[(size_t)l * NPTS + base + t]);

    __syncthreads();

    #pragma unroll
    for (int it = 0; it < 8; ++it) {
        const unsigned j = it * 256 + t;
        const unsigned pl = j >> 3;          // local sorted point
        const unsigned k = j & 7u;           // level pair
        const v2f a = lds[(2u * k)      * P2S + pl];
        const v2f b = lds[(2u * k + 1u) * P2S + pl];
        v4f v = { a.x, a.y, b.x, b.y };
        __builtin_nontemporal_store(
            v, (v4f*)(out + (size_t)nperm[pl] * 32 + k * 4));
    }
}

// ---------------------------------------------------------------------------
// Fallback single-kernel (used only if ws_size is too small).
// ---------------------------------------------------------------------------
__global__ __launch_bounds__(256) void ngp_encode(
    const float* __restrict__ xyz,
    const float* __restrict__ tables,
    float* __restrict__ out,
    LevelParams lp)
{
    const int n = blockIdx.x * 256 + threadIdx.x;
    const float x = xyz[3 * n + 0];
    const float y = xyz[3 * n + 1];
    const float z = xyz[3 * n + 2];

    float acc[2 * NLEVELS];
    const v2f* __restrict__ tab_base = (const v2f*)tables;

    #pragma unroll
    for (int l = 0; l < NLEVELS; ++l) {
        unsigned h[8];
        float dx, dy, dz;
        ngp_hash(x, y, z, lp.cell[l], h, dx, dy, dz);
        const v2f* __restrict__ tab = tab_base + ((size_t)l << 19);
        v2f e[8];
        #pragma unroll
        for (int c = 0; c < 8; ++c) e[c] = tab[h[c]];
        float w[8];
        ngp_weights(dx, dy, dz, w);
        const v2f r = ngp_combine(w, e);
        acc[2 * l + 0] = r.x;
        acc[2 * l + 1] = r.y;
    }

    v4f* o4 = (v4f*)(out + (size_t)n * 32);
    #pragma unroll
    for (int j = 0; j < 8; ++j) {
        v4f v = { acc[4 * j + 0], acc[4 * j + 1],
                  acc[4 * j + 2], acc[4 * j + 3] };
        o4[j] = v;
    }
}

extern "C" void kernel_launch(void* const* d_in, const int* in_sizes, int n_in,
                              void* d_out, int out_size, void* d_ws, size_t ws_size,
                              hipStream_t stream) {
    const float* xyz    = (const float*)d_in[0];
    const float* tables = (const float*)d_in[1];
    float* out          = (float*)d_out;

    // Compute RES exactly as CPython does (glibc double exp/log/pow), then
    // cell = 1/RES in fp32 exactly as numpy float32 division.
    LevelParams lp;
    const double B = std::exp((std::log(2048.0) - std::log(16.0)) / 15.0);
    for (int i = 0; i < NLEVELS; ++i) {
        const double r = std::floor(16.0 * std::pow(B, (double)i));
        lp.cell[i] = 1.0f / (float)r;
    }

    // Workspace layout (16B-aligned blocks):
    //   [0, 64MB)        v2f ws_feat[L][N]
    //   [64MB, +8MB)     v4f pts[N]           (x, y, z, bits(orig_index))
    //   [+128KB)         u32 counts[NBUCKET]
    //   [+128KB)         u32 cursor[NBUCKET]
    const size_t off_feat   = 0;
    const size_t off_pts    = off_feat + (size_t)NLEVELS * NPTS * sizeof(v2f);
    const size_t off_counts = off_pts + (size_t)NPTS * sizeof(v4f);
    const size_t off_cursor = off_counts + (size_t)NBUCKET * sizeof(unsigned);
    const size_t ws_needed  = off_cursor + (size_t)NBUCKET * sizeof(unsigned);

    if (ws_size >= ws_needed) {
        char* wsb = (char*)d_ws;
        v2f*      ws_feat = (v2f*)(wsb + off_feat);
        v4f*      pts     = (v4f*)(wsb + off_pts);
        unsigned* counts  = (unsigned*)(wsb + off_counts);
        unsigned* cursor  = (unsigned*)(wsb + off_cursor);

        hipMemsetAsync(counts, 0, NBUCKET * sizeof(unsigned), stream);
        hipLaunchKernelGGL(bucket_count, dim3(NPTS / 256), dim3(256), 0, stream,
                           xyz, counts);
        hipLaunchKernelGGL(bucket_scan, dim3(1), dim3(1024), 0, stream,
                           counts, cursor);
        hipLaunchKernelGGL(bucket_scatter, dim3(NPTS / 256), dim3(256), 0, stream,
                           xyz, cursor, pts);
        hipLaunchKernelGGL(ngp_phase1, dim3(NLEVELS * (NPTS / 512)), dim3(256), 0, stream,
                           pts, tables, ws_feat, lp);
        hipLaunchKernelGGL(ngp_phase2, dim3(NPTS / 256), dim3(256), 0, stream,
                           ws_feat, pts, out);
    } else {
        hipLaunchKernelGGL(ngp_encode, dim3(NPTS / 256), dim3(256), 0, stream,
                           xyz, tables, out, lp);
    }
}